// Round 18
// baseline (495.126 us; speedup 1.0000x reference)
//
#include <hip/hip_runtime.h>
#include <hip/hip_fp16.h>

// ---------------------------------------------------------------------------
// MaskedGNN: 6-layer GCN, weight-free scaled-hidden formulation.
//  Hidden state H' = dis*h, fp16, SLICE-MAJOR layout [2][N][64] (slice =
//  12.8MB). Per layer (SPLIT):
//    agg:  z = dis*(sum_src H'_src + H'_self), per slice; XCD-steered
//          (slice 0 -> XCDs 0-3, slice 1 -> XCDs 4-7). Neighbor lists are
//          SORTED ASCENDING by src -> concurrent waves sweep the slice in a
//          sliding window (~L2-sized) -> capacity misses -> compulsory.
//    gemm: h' = dis*relu(z @ W + b)  [W staged in XOR-swizzled LDS, MFMA]
//  CSR: LDS-radix partition by dst>>7; k_build insertion-sorts each row.
//  GEMM: MFMA f32_16x16x32_f16, W split hi/lo fp16 (W exact), fp32 accum,
//  in place on the Z buffer; last layer's gemm emits the decoder matvec.
// ---------------------------------------------------------------------------

#define HW 128     // hidden width
#define NBMAX 1024 // max dst buckets (N <= 131072)
#define CAP 4096   // max edges per bucket staged in LDS
#define PBLK 256   // partition blocks (== threads in k_soff2)
#define GBR 256    // rows per gemm block

typedef _Float16 f16x8 __attribute__((ext_vector_type(8)));
typedef float f32x4 __attribute__((ext_vector_type(4)));

// ---------------- CSR build ----------------
__global__ void k_zero_i32(int* __restrict__ a, int n) {
    int i = blockIdx.x * 256 + threadIdx.x;
    if (i < n) a[i] = 0;
}

// per-block LDS bucket histogram; saves per-block counts + global bucket sums
__global__ __launch_bounds__(256) void k_histb(const int* __restrict__ dstA,
                                               int* __restrict__ bcnt,
                                               int* __restrict__ pcnt,
                                               int nb, int e, int nblk) {
    __shared__ int lh[NBMAX];
    for (int b = threadIdx.x; b < nb; b += 256) lh[b] = 0;
    __syncthreads();
    int blk = blockIdx.x;
    int c0 = (int)(((long long)e * blk) / nblk);
    int c1 = (int)(((long long)e * (blk + 1)) / nblk);
    for (int i = c0 + threadIdx.x; i < c1; i += 256) atomicAdd(&lh[dstA[i] >> 7], 1);
    __syncthreads();
    for (int b = threadIdx.x; b < nb; b += 256) {
        int v = lh[b];
        pcnt[(size_t)blk * nb + b] = v;
        if (v) atomicAdd(&bcnt[b], v);
    }
}

__global__ void k_bscan(const int* __restrict__ bcnt, int* __restrict__ bstart,
                        int nb, int etot) {
    __shared__ int s[1024];
    int t = threadIdx.x;
    int d0 = (t < nb) ? bcnt[t] : 0;
    s[t] = d0;
    __syncthreads();
    for (int off = 1; off < 1024; off <<= 1) {
        int v = (t >= off) ? s[t - off] : 0;
        __syncthreads();
        s[t] += v;
        __syncthreads();
    }
    if (t < nb) bstart[t] = s[t] - d0;
    if (t == 0) bstart[nb] = etot;
}

// per-bucket scan of the PBLK per-block counts -> exact staging offsets
__global__ __launch_bounds__(PBLK) void k_soff2(const int* __restrict__ pcnt,
                                                const int* __restrict__ bstart,
                                                int* __restrict__ soff, int nb) {
    __shared__ int s[PBLK];
    int b = blockIdx.x, t = threadIdx.x;
    int v = pcnt[(size_t)t * nb + b];
    s[t] = v;
    __syncthreads();
    for (int off = 1; off < PBLK; off <<= 1) {
        int u = (t >= off) ? s[t - off] : 0;
        __syncthreads();
        s[t] += u;
        __syncthreads();
    }
    soff[(size_t)t * nb + b] = bstart[b] + s[t] - v;
}

// partition edges into bucket windows using precomputed offsets.
// stage = (src<<7)|(dst&127).
__global__ __launch_bounds__(256) void k_part(const int* __restrict__ srcA,
                                              const int* __restrict__ dstA,
                                              const int* __restrict__ soff,
                                              unsigned* __restrict__ stage,
                                              int nb, int e, int nblk) {
    __shared__ int loff[NBMAX];
    __shared__ int lh[NBMAX];
    int blk = blockIdx.x;
    for (int b = threadIdx.x; b < nb; b += 256) {
        loff[b] = soff[(size_t)blk * nb + b];
        lh[b] = 0;
    }
    __syncthreads();
    int c0 = (int)(((long long)e * blk) / nblk);
    int c1 = (int)(((long long)e * (blk + 1)) / nblk);
    for (int i = c0 + threadIdx.x; i < c1; i += 256) {
        int d = dstA[i];
        int bk = d >> 7;
        int p = loff[bk] + atomicAdd(&lh[bk], 1);
        stage[p] = ((unsigned)srcA[i] << 7) | (unsigned)(d & 127);
    }
}

// one block per bucket: count+scan -> row_start/dis/x4, LDS placement,
// per-row ascending insertion sort -> coalesced csr window write.
__global__ __launch_bounds__(256) void k_build(const unsigned* __restrict__ stage,
                                               const int* __restrict__ bstart,
                                               const float* __restrict__ x,
                                               int* __restrict__ row_start,
                                               float* __restrict__ dis,
                                               float4* __restrict__ x4,
                                               int* __restrict__ csr, int n, int nb) {
    __shared__ int lcnt[128];
    __shared__ int sc[128];
    __shared__ int lcsr[CAP];
    int b = blockIdx.x, tid = threadIdx.x;
    int base = bstart[b], end = bstart[b + 1], cnt = end - base;
    int node0 = b << 7;

    if (tid < 128) lcnt[tid] = 0;
    __syncthreads();
    for (int j = tid; j < cnt; j += 256) atomicAdd(&lcnt[stage[base + j] & 127], 1);
    __syncthreads();
    if (tid < 128) sc[tid] = lcnt[tid];
    __syncthreads();
    for (int off = 1; off < 128; off <<= 1) {
        int v = (tid < 128 && tid >= off) ? sc[tid - off] : 0;
        __syncthreads();
        if (tid < 128) sc[tid] += v;
        __syncthreads();
    }
    int node = node0 + tid;
    if (tid < 128 && node < n) {
        int excl = sc[tid] - lcnt[tid];
        row_start[node] = base + excl;
        float dv = rsqrtf(1.f + (float)lcnt[tid]);
        dis[node] = dv;
        x4[node] = make_float4(x[node * 3] * dv, x[node * 3 + 1] * dv,
                               x[node * 3 + 2] * dv, 0.f);
    }
    if (tid == 0 && b == nb - 1) row_start[n] = end;
    __syncthreads();
    if (tid < 128) sc[tid] = sc[tid] - lcnt[tid];  // exclusive offsets
    if (tid < 128) lcnt[tid] = 0;
    __syncthreads();
    if (cnt <= CAP) {
        for (int j = tid; j < cnt; j += 256) {
            unsigned v = stage[base + j];
            int dl = v & 127;
            int p = atomicAdd(&lcnt[dl], 1);
            lcsr[sc[dl] + p] = (int)(v >> 7);
        }
        __syncthreads();
        // per-row ascending insertion sort (thread tid owns row tid):
        // enables the sliding-src-window locality in the aggregator.
        if (tid < 128) {
            int lo = sc[tid], hi = lo + lcnt[tid];
            for (int a = lo + 1; a < hi; ++a) {
                int v = lcsr[a];
                int c = a - 1;
                while (c >= lo && lcsr[c] > v) { lcsr[c + 1] = lcsr[c]; --c; }
                lcsr[c + 1] = v;
            }
        }
        __syncthreads();
        for (int j = tid; j < cnt; j += 256) csr[base + j] = lcsr[j];
    } else {  // pathological bucket (never for this N,E): unsorted fallback
        for (int j = tid; j < cnt; j += 256) {
            unsigned v = stage[base + j];
            int dl = v & 127;
            int p = atomicAdd(&lcnt[dl], 1);
            csr[base + sc[dl] + p] = (int)(v >> 7);
        }
    }
}

// ---------------- W prep: transpose + hi/lo fp16 split ----------------
__global__ void k_prep_wt(const float* __restrict__ Wp, __half* __restrict__ WTh,
                          __half* __restrict__ WTl, int total) {
    int t = blockIdx.x * 256 + threadIdx.x;
    if (t >= total) return;
    int l = t >> 14;
    int kc = t & 16383;
    int k = kc >> 7, c = kc & 127;
    float w = Wp[t];
    __half hi = __float2half_rn(w);
    __half lo = __float2half_rn(w - __half2float(hi));
    size_t o = ((size_t)l << 14) + (size_t)c * HW + k;
    WTh[o] = hi;
    WTl[o] = lo;
}

// ---------------- encoder ----------------
__global__ void k_enc_agg(const float4* __restrict__ x4, const int* __restrict__ rs,
                          const int* __restrict__ csr, const float* __restrict__ dis,
                          float4* __restrict__ zx, int n) {
    int i = blockIdx.x * 256 + threadIdx.x;
    if (i >= n) return;
    float4 a = x4[i];
    int e1 = rs[i + 1];
    for (int j = rs[i]; j < e1; ++j) {
        float4 v = x4[csr[j]];
        a.x += v.x; a.y += v.y; a.z += v.z;
    }
    float d = dis[i];
    zx[i] = make_float4(a.x * d, a.y * d, a.z * d, 0.f);
}

// writes H in slice-major layout: H[(c>>6)*n + i][c&63]
__global__ void k_enc_gemm(const float4* __restrict__ zx, const float* __restrict__ We,
                           const float* __restrict__ be, const float* __restrict__ dis,
                           __half* __restrict__ H, int n) {
    int t = blockIdx.x * 256 + threadIdx.x;
    int i = t >> 7;
    int c = t & 127;
    if (i >= n) return;
    float4 z = zx[i];
    float v = z.x * We[c] + z.y * We[HW + c] + z.z * We[2 * HW + c] + be[c];
    H[((size_t)(c >> 6) * n + i) * 64 + (c & 63)] = __float2half_rn(fmaxf(v, 0.f) * dis[i]);
}

// ---------------- S=2 sliced aggregate, XCD-steered, sorted-src rows --------
// Block group of 8: chunks c..c+3 of slice 0 on XCDs 0-3, slice 1 on 4-7.
// Wave = 8 nodes x 8 lanes x 16B (128B slice-row), 4-deep unroll.
__global__ __launch_bounds__(256) void k_agg_s2(const __half* __restrict__ Hin,
                                                const int* __restrict__ rs,
                                                const int* __restrict__ csr,
                                                const float* __restrict__ dis,
                                                __half* __restrict__ Z, int n) {
    int b = blockIdx.x;
    int chunk = (b >> 3) * 4 + (b & 3);
    int s = (b >> 2) & 1;
    int wave = threadIdx.x >> 6, lane = threadIdx.x & 63;
    int lg = lane & 7;   // lane in 8-lane group
    int node = chunk * 32 + wave * 8 + (lane >> 3);
    bool active = node < n;
    const __half* Hs = Hin + (size_t)s * n * 64;

    float a0[8], a1[8], a2[8], a3[8];
#pragma unroll
    for (int j = 0; j < 8; ++j) { a0[j] = 0.f; a1[j] = 0.f; a2[j] = 0.f; a3[j] = 0.f; }

    int e0 = 0, e1 = 0;
    if (active) {
        e0 = rs[node];
        e1 = rs[node + 1];
        f16x8 hv = *(const f16x8*)(Hs + (size_t)node * 64 + lg * 8);
#pragma unroll
        for (int j = 0; j < 8; ++j) a0[j] = (float)hv[j];
    }

    for (int base = e0; base < e1; base += 8) {
        int cnt = e1 - base;
        if (cnt > 8) cnt = 8;
        int sl = (base + lg < e1) ? csr[base + lg] : 0;
        int k = 0;
        for (; k + 4 <= cnt; k += 4) {
            int s0 = __shfl(sl, k + 0, 8);
            int s1 = __shfl(sl, k + 1, 8);
            int s2 = __shfl(sl, k + 2, 8);
            int s3 = __shfl(sl, k + 3, 8);
            f16x8 v0 = *(const f16x8*)(Hs + (size_t)s0 * 64 + lg * 8);
            f16x8 v1 = *(const f16x8*)(Hs + (size_t)s1 * 64 + lg * 8);
            f16x8 v2 = *(const f16x8*)(Hs + (size_t)s2 * 64 + lg * 8);
            f16x8 v3 = *(const f16x8*)(Hs + (size_t)s3 * 64 + lg * 8);
#pragma unroll
            for (int j = 0; j < 8; ++j) {
                a0[j] += (float)v0[j];
                a1[j] += (float)v1[j];
                a2[j] += (float)v2[j];
                a3[j] += (float)v3[j];
            }
        }
        for (; k < cnt; ++k) {
            int sk = __shfl(sl, k, 8);
            f16x8 v = *(const f16x8*)(Hs + (size_t)sk * 64 + lg * 8);
#pragma unroll
            for (int j = 0; j < 8; ++j) a0[j] += (float)v[j];
        }
    }

    if (active) {
        float d = dis[node];
        union { uint4 u; __half2 h[4]; } pk;
#pragma unroll
        for (int j = 0; j < 4; ++j) {
            float lo = d * ((a0[2 * j] + a1[2 * j]) + (a2[2 * j] + a3[2 * j]));
            float hi = d * ((a0[2 * j + 1] + a1[2 * j + 1]) + (a2[2 * j + 1] + a3[2 * j + 1]));
            pk.h[j] = __floats2half2_rn(lo, hi);
        }
        *(uint4*)(Z + ((size_t)s * n + node) * 64 + lg * 8) = pk.u;
    }
}

// ---------------- MFMA GEMM, W in LDS: H' = dis*relu(Z@W+b), in place -------
// 256 threads = 4 waves; block stages WTh+WTl (64KB) into XOR-swizzled LDS
// once, then processes GBR=256 rows (wave = 16 rows/iter, 4 iters).
// Z/H in slice-major [2][N][64]: A-frag slice = ks>>1, off = (ks&1)*32.
// mode 1 (last layer): emit t[row] = (relu-row . Wd) via 16-lane shfl reduce.
__global__ __launch_bounds__(256) void k_gemmw(const __half* __restrict__ Z,
                                               const __half* __restrict__ WTh,
                                               const __half* __restrict__ WTl,
                                               const float* __restrict__ b,
                                               const float* __restrict__ dis,
                                               __half* __restrict__ Hout,
                                               const float* __restrict__ Wd,
                                               float* __restrict__ tout,
                                               int mode, int n) {
    __shared__ __half ws[2][128][128];  // 64KB, swizzled
    int tid = threadIdx.x;
    int wave = tid >> 6, lane = tid & 63;
    int q = lane >> 4, r16 = lane & 15;

    // ---- stage W (coalesced 16B/thread x 16 passes) ----
#pragma unroll
    for (int p = 0; p < 16; ++p) {
        int idx = p * 256 + tid;       // 0..4095 16B-slots
        int slot = idx & 15;
        int col = (idx >> 4) & 127;
        int hl = idx >> 11;
        const __half* src = hl ? WTl : WTh;
        f16x8 v = *(const f16x8*)(src + (size_t)col * HW + slot * 8);
        *(f16x8*)(&ws[hl][col][(slot ^ (col & 7)) * 8]) = v;
    }
    __syncthreads();

    for (int rt = 0; rt < GBR / 64; ++rt) {
        int row0 = blockIdx.x * GBR + rt * 64 + wave * 16;
        if (row0 >= n) break;  // per-wave exit; no syncs below

        f16x8 afr[4];
#pragma unroll
        for (int ks = 0; ks < 4; ++ks) {
            int row = row0 + r16;
            row = row < n ? row : (n - 1);  // clamp; results discarded at store
            afr[ks] = *(const f16x8*)(Z + ((size_t)(ks >> 1) * n + row) * 64 +
                                      (ks & 1) * 32 + q * 8);
        }

        f32x4 acc[8];
#pragma unroll
        for (int nt = 0; nt < 8; ++nt) acc[nt] = (f32x4)0.f;
#pragma unroll
        for (int ks = 0; ks < 4; ++ks) {
            int sslot = ((ks * 4 + q) ^ (r16 & 7)) * 8;
#pragma unroll
            for (int nt = 0; nt < 8; ++nt) {
                int col = nt * 16 + r16;
                f16x8 bh = *(const f16x8*)(&ws[0][col][sslot]);
                f16x8 bl = *(const f16x8*)(&ws[1][col][sslot]);
                acc[nt] = __builtin_amdgcn_mfma_f32_16x16x32_f16(afr[ks], bh, acc[nt], 0, 0, 0);
                acc[nt] = __builtin_amdgcn_mfma_f32_16x16x32_f16(afr[ks], bl, acc[nt], 0, 0, 0);
            }
        }

        if (mode == 0) {
#pragma unroll
            for (int nt = 0; nt < 8; ++nt) {
                int col = nt * 16 + r16;
                int cs = col >> 6, c64 = col & 63;
                float bias = b[col];
#pragma unroll
                for (int r = 0; r < 4; ++r) {
                    int row = row0 + q * 4 + r;
                    if (row < n) {
                        float v = fmaxf(acc[nt][r] + bias, 0.f) * dis[row];
                        Hout[((size_t)cs * n + row) * 64 + c64] = __float2half_rn(v);
                    }
                }
            }
        } else {
            float pr[4] = {0.f, 0.f, 0.f, 0.f};
#pragma unroll
            for (int nt = 0; nt < 8; ++nt) {
                int col = nt * 16 + r16;
                float bias = b[col];
                float wd = Wd[col];
#pragma unroll
                for (int r = 0; r < 4; ++r)
                    pr[r] += fmaxf(acc[nt][r] + bias, 0.f) * wd;
            }
#pragma unroll
            for (int r = 0; r < 4; ++r) {
#pragma unroll
                for (int off = 1; off < 16; off <<= 1) pr[r] += __shfl_xor(pr[r], off, 16);
                if (r16 == 0) {
                    int row = row0 + q * 4 + r;
                    if (row < n) tout[row] = pr[r] * dis[row];
                }
            }
        }
    }
}

// ---------------- decoder output ----------------
__global__ void k_dec_out(const float* __restrict__ t, const int* __restrict__ rs,
                          const int* __restrict__ csr, const float* __restrict__ dis,
                          const float* __restrict__ bdec, const float* __restrict__ mask,
                          float* __restrict__ out, int n) {
    int i = blockIdx.x * 256 + threadIdx.x;
    if (i >= n) return;
    float acc = t[i];
    int e1 = rs[i + 1];
    for (int j = rs[i]; j < e1; ++j) acc += t[csr[j]];
    out[i] = (dis[i] * acc + bdec[0]) * mask[i];
}

// ---------------------------------------------------------------------------
static inline size_t align256(size_t x) { return (x + 255) & ~(size_t)255; }

extern "C" void kernel_launch(void* const* d_in, const int* in_sizes, int n_in,
                              void* d_out, int out_size, void* d_ws, size_t ws_size,
                              hipStream_t stream) {
    const float* x     = (const float*)d_in[0];
    const float* mask  = (const float*)d_in[1];
    const int*   ei    = (const int*)d_in[2];
    const float* W_enc = (const float*)d_in[3];
    const float* b_enc = (const float*)d_in[4];
    const float* W_p   = (const float*)d_in[5];
    const float* b_p   = (const float*)d_in[6];
    const float* W_dec = (const float*)d_in[7];
    const float* b_dec = (const float*)d_in[8];

    const int N = in_sizes[1];
    const int E = in_sizes[2] / 2;
    const int* srcA = ei;
    const int* dstA = ei + E;
    const int NB = (N + 127) >> 7;  // dst buckets of 128 nodes (<= NBMAX)

    char* p = (char*)d_ws;
    size_t off = 0;
    auto carve = [&](size_t bytes) {
        void* r = p + off;
        off += align256(bytes);
        return r;
    };
    int*      bcnt      = (int*)carve((size_t)NB * 4);
    int*      bstart    = (int*)carve((size_t)(NB + 1) * 4);
    int*      pcnt      = (int*)carve((size_t)PBLK * NB * 4);
    int*      soff      = (int*)carve((size_t)PBLK * NB * 4);
    int*      row_start = (int*)carve((size_t)(N + 1) * 4);
    unsigned* stage     = (unsigned*)carve((size_t)E * 4);
    int*      csr       = (int*)carve((size_t)E * 4);
    float*    dis       = (float*)carve((size_t)N * 4);
    float4*   x4        = (float4*)carve((size_t)N * 16);
    float4*   zx        = (float4*)carve((size_t)N * 16);
    float*    tdec      = (float*)carve((size_t)N * 4);
    __half*   WTh       = (__half*)carve((size_t)4 * HW * HW * 2);
    __half*   WTl       = (__half*)carve((size_t)4 * HW * HW * 2);
    __half*   HA        = (__half*)carve((size_t)N * HW * 2);
    __half*   HB        = (__half*)carve((size_t)N * HW * 2);

    const int gN   = (N + 255) / 256;
    const int nChunk = (N + 31) / 32;
    const int gAgg = ((nChunk + 3) / 4) * 8;
    const int gG   = (N + GBR - 1) / GBR;
    const int WPT  = 4 * HW * HW;

    // ---- CSR build (LDS-radix, sorted rows) + preps ----
    k_zero_i32<<<(NB + 255) / 256, 256, 0, stream>>>(bcnt, NB);
    k_histb<<<PBLK, 256, 0, stream>>>(dstA, bcnt, pcnt, NB, E, PBLK);
    k_bscan<<<1, 1024, 0, stream>>>(bcnt, bstart, NB, E);
    k_soff2<<<NB, PBLK, 0, stream>>>(pcnt, bstart, soff, NB);
    k_part<<<PBLK, 256, 0, stream>>>(srcA, dstA, soff, stage, NB, E, PBLK);
    k_build<<<NB, 256, 0, stream>>>(stage, bstart, x, row_start, dis, x4, csr, N, NB);
    k_prep_wt<<<(WPT + 255) / 256, 256, 0, stream>>>(W_p, WTh, WTl, WPT);

    // ---- encoder ----
    k_enc_agg<<<gN, 256, 0, stream>>>(x4, row_start, csr, dis, zx, N);
    k_enc_gemm<<<(N * HW + 255) / 256, 256, 0, stream>>>(zx, W_enc, b_enc, dis, HA, N);

    // ---- 4 processor layers: sliced agg(Hin->Hoth), gemmw in place on Hoth -
    __half* Hin = HA;
    __half* Hoth = HB;
    for (int l = 0; l < 4; ++l) {
        k_agg_s2<<<gAgg, 256, 0, stream>>>(Hin, row_start, csr, dis, Hoth, N);
        int mode = (l == 3) ? 1 : 0;
        k_gemmw<<<gG, 256, 0, stream>>>(Hoth, WTh + (size_t)l * HW * HW,
                                        WTl + (size_t)l * HW * HW,
                                        b_p + (size_t)l * HW, dis, Hoth,
                                        W_dec, tdec, mode, N);
        __half* t = Hin; Hin = Hoth; Hoth = t;
    }

    // ---- decoder output ----
    k_dec_out<<<gN, 256, 0, stream>>>(tdec, row_start, csr, dis, b_dec, mask,
                                      (float*)d_out, N);
}

// Round 19
// 462.940 us; speedup vs baseline: 1.0695x; 1.0695x over previous
//
#include <hip/hip_runtime.h>
#include <hip/hip_fp16.h>

// ---------------------------------------------------------------------------
// MaskedGNN: 6-layer GCN, weight-free scaled-hidden formulation.
//  Hidden state H' = dis*h, fp16, SLICE-MAJOR layout [2][N][64] (slice =
//  12.8MB). Per layer (SPLIT):
//    agg:  z = dis*(sum_src H'_src + H'_self), per slice; XCD-steered
//          (slice 0 -> XCDs 0-3, slice 1 -> XCDs 4-7). 8 lanes/node x 16B
//          (128B slice-row), 4-deep unroll.
//    gemm: h' = dis*relu(z @ W + b)  [W staged in XOR-swizzled LDS, MFMA]
//  CSR: LDS-radix partition by dst>>7 (R12-proven build chain, unsorted).
//  GEMM: MFMA f32_16x16x32_f16, W split hi/lo fp16 (W exact), fp32 accum,
//  in place on the Z buffer; last layer's gemm emits the decoder matvec.
//  Operating point (measured R17): agg 59us/layer @166MB L2-miss traffic,
//  ~3.3TB/s fabric service, 0 bank conflicts -- the random-128B L2/L3
//  service ceiling for this graph. Fusion/slicing/sorting variants all
//  measured slower (R9/R10/R13/R14/R18).
// ---------------------------------------------------------------------------

#define HW 128     // hidden width
#define NBMAX 1024 // max dst buckets (N <= 131072)
#define CAP 4096   // max edges per bucket staged in LDS
#define PBLK 256   // partition blocks (== threads in k_soff2)
#define GBR 256    // rows per gemm block

typedef _Float16 f16x8 __attribute__((ext_vector_type(8)));
typedef float f32x4 __attribute__((ext_vector_type(4)));

// ---------------- CSR build ----------------
__global__ void k_zero_i32(int* __restrict__ a, int n) {
    int i = blockIdx.x * 256 + threadIdx.x;
    if (i < n) a[i] = 0;
}

// per-block LDS bucket histogram; saves per-block counts + global bucket sums
__global__ __launch_bounds__(256) void k_histb(const int* __restrict__ dstA,
                                               int* __restrict__ bcnt,
                                               int* __restrict__ pcnt,
                                               int nb, int e, int nblk) {
    __shared__ int lh[NBMAX];
    for (int b = threadIdx.x; b < nb; b += 256) lh[b] = 0;
    __syncthreads();
    int blk = blockIdx.x;
    int c0 = (int)(((long long)e * blk) / nblk);
    int c1 = (int)(((long long)e * (blk + 1)) / nblk);
    for (int i = c0 + threadIdx.x; i < c1; i += 256) atomicAdd(&lh[dstA[i] >> 7], 1);
    __syncthreads();
    for (int b = threadIdx.x; b < nb; b += 256) {
        int v = lh[b];
        pcnt[(size_t)blk * nb + b] = v;
        if (v) atomicAdd(&bcnt[b], v);
    }
}

__global__ void k_bscan(const int* __restrict__ bcnt, int* __restrict__ bstart,
                        int nb, int etot) {
    __shared__ int s[1024];
    int t = threadIdx.x;
    int d0 = (t < nb) ? bcnt[t] : 0;
    s[t] = d0;
    __syncthreads();
    for (int off = 1; off < 1024; off <<= 1) {
        int v = (t >= off) ? s[t - off] : 0;
        __syncthreads();
        s[t] += v;
        __syncthreads();
    }
    if (t < nb) bstart[t] = s[t] - d0;
    if (t == 0) bstart[nb] = etot;
}

// per-bucket scan of the PBLK per-block counts -> exact staging offsets
__global__ __launch_bounds__(PBLK) void k_soff2(const int* __restrict__ pcnt,
                                                const int* __restrict__ bstart,
                                                int* __restrict__ soff, int nb) {
    __shared__ int s[PBLK];
    int b = blockIdx.x, t = threadIdx.x;
    int v = pcnt[(size_t)t * nb + b];
    s[t] = v;
    __syncthreads();
    for (int off = 1; off < PBLK; off <<= 1) {
        int u = (t >= off) ? s[t - off] : 0;
        __syncthreads();
        s[t] += u;
        __syncthreads();
    }
    soff[(size_t)t * nb + b] = bstart[b] + s[t] - v;
}

// partition edges into bucket windows using precomputed offsets.
// stage = (src<<7)|(dst&127).
__global__ __launch_bounds__(256) void k_part(const int* __restrict__ srcA,
                                              const int* __restrict__ dstA,
                                              const int* __restrict__ soff,
                                              unsigned* __restrict__ stage,
                                              int nb, int e, int nblk) {
    __shared__ int loff[NBMAX];
    __shared__ int lh[NBMAX];
    int blk = blockIdx.x;
    for (int b = threadIdx.x; b < nb; b += 256) {
        loff[b] = soff[(size_t)blk * nb + b];
        lh[b] = 0;
    }
    __syncthreads();
    int c0 = (int)(((long long)e * blk) / nblk);
    int c1 = (int)(((long long)e * (blk + 1)) / nblk);
    for (int i = c0 + threadIdx.x; i < c1; i += 256) {
        int d = dstA[i];
        int bk = d >> 7;
        int p = loff[bk] + atomicAdd(&lh[bk], 1);
        stage[p] = ((unsigned)srcA[i] << 7) | (unsigned)(d & 127);
    }
}

// one block per bucket: count+scan -> row_start/dis/x4, LDS placement ->
// coalesced csr window write.
__global__ __launch_bounds__(256) void k_build(const unsigned* __restrict__ stage,
                                               const int* __restrict__ bstart,
                                               const float* __restrict__ x,
                                               int* __restrict__ row_start,
                                               float* __restrict__ dis,
                                               float4* __restrict__ x4,
                                               int* __restrict__ csr, int n, int nb) {
    __shared__ int lcnt[128];
    __shared__ int sc[128];
    __shared__ int lcsr[CAP];
    int b = blockIdx.x, tid = threadIdx.x;
    int base = bstart[b], end = bstart[b + 1], cnt = end - base;
    int node0 = b << 7;

    if (tid < 128) lcnt[tid] = 0;
    __syncthreads();
    for (int j = tid; j < cnt; j += 256) atomicAdd(&lcnt[stage[base + j] & 127], 1);
    __syncthreads();
    if (tid < 128) sc[tid] = lcnt[tid];
    __syncthreads();
    for (int off = 1; off < 128; off <<= 1) {
        int v = (tid < 128 && tid >= off) ? sc[tid - off] : 0;
        __syncthreads();
        if (tid < 128) sc[tid] += v;
        __syncthreads();
    }
    int node = node0 + tid;
    if (tid < 128 && node < n) {
        int excl = sc[tid] - lcnt[tid];
        row_start[node] = base + excl;
        float dv = rsqrtf(1.f + (float)lcnt[tid]);
        dis[node] = dv;
        x4[node] = make_float4(x[node * 3] * dv, x[node * 3 + 1] * dv,
                               x[node * 3 + 2] * dv, 0.f);
    }
    if (tid == 0 && b == nb - 1) row_start[n] = end;
    __syncthreads();
    if (tid < 128) sc[tid] = sc[tid] - lcnt[tid];  // exclusive offsets
    if (tid < 128) lcnt[tid] = 0;
    __syncthreads();
    if (cnt <= CAP) {
        for (int j = tid; j < cnt; j += 256) {
            unsigned v = stage[base + j];
            int dl = v & 127;
            int p = atomicAdd(&lcnt[dl], 1);
            lcsr[sc[dl] + p] = (int)(v >> 7);
        }
        __syncthreads();
        for (int j = tid; j < cnt; j += 256) csr[base + j] = lcsr[j];
    } else {
        for (int j = tid; j < cnt; j += 256) {
            unsigned v = stage[base + j];
            int dl = v & 127;
            int p = atomicAdd(&lcnt[dl], 1);
            csr[base + sc[dl] + p] = (int)(v >> 7);
        }
    }
}

// ---------------- W prep: transpose + hi/lo fp16 split ----------------
__global__ void k_prep_wt(const float* __restrict__ Wp, __half* __restrict__ WTh,
                          __half* __restrict__ WTl, int total) {
    int t = blockIdx.x * 256 + threadIdx.x;
    if (t >= total) return;
    int l = t >> 14;
    int kc = t & 16383;
    int k = kc >> 7, c = kc & 127;
    float w = Wp[t];
    __half hi = __float2half_rn(w);
    __half lo = __float2half_rn(w - __half2float(hi));
    size_t o = ((size_t)l << 14) + (size_t)c * HW + k;
    WTh[o] = hi;
    WTl[o] = lo;
}

// ---------------- encoder ----------------
__global__ void k_enc_agg(const float4* __restrict__ x4, const int* __restrict__ rs,
                          const int* __restrict__ csr, const float* __restrict__ dis,
                          float4* __restrict__ zx, int n) {
    int i = blockIdx.x * 256 + threadIdx.x;
    if (i >= n) return;
    float4 a = x4[i];
    int e1 = rs[i + 1];
    for (int j = rs[i]; j < e1; ++j) {
        float4 v = x4[csr[j]];
        a.x += v.x; a.y += v.y; a.z += v.z;
    }
    float d = dis[i];
    zx[i] = make_float4(a.x * d, a.y * d, a.z * d, 0.f);
}

// writes H in slice-major layout: H[(c>>6)*n + i][c&63]
__global__ void k_enc_gemm(const float4* __restrict__ zx, const float* __restrict__ We,
                           const float* __restrict__ be, const float* __restrict__ dis,
                           __half* __restrict__ H, int n) {
    int t = blockIdx.x * 256 + threadIdx.x;
    int i = t >> 7;
    int c = t & 127;
    if (i >= n) return;
    float4 z = zx[i];
    float v = z.x * We[c] + z.y * We[HW + c] + z.z * We[2 * HW + c] + be[c];
    H[((size_t)(c >> 6) * n + i) * 64 + (c & 63)] = __float2half_rn(fmaxf(v, 0.f) * dis[i]);
}

// ---------------- S=2 sliced aggregate, XCD-steered ----------------
// Block group of 8: chunks c..c+3 of slice 0 on XCDs 0-3 (blockIdx%8 round
// robin), chunks c..c+3 of slice 1 on XCDs 4-7. Block = 32 nodes x 1 slice.
// Wave = 8 nodes x 8 lanes x 16B (128B slice-row), 4-deep unroll.
__global__ __launch_bounds__(256) void k_agg_s2(const __half* __restrict__ Hin,
                                                const int* __restrict__ rs,
                                                const int* __restrict__ csr,
                                                const float* __restrict__ dis,
                                                __half* __restrict__ Z, int n) {
    int b = blockIdx.x;
    int chunk = (b >> 3) * 4 + (b & 3);
    int s = (b >> 2) & 1;
    int wave = threadIdx.x >> 6, lane = threadIdx.x & 63;
    int lg = lane & 7;   // lane in 8-lane group
    int node = chunk * 32 + wave * 8 + (lane >> 3);
    bool active = node < n;
    const __half* Hs = Hin + (size_t)s * n * 64;

    float a0[8], a1[8], a2[8], a3[8];
#pragma unroll
    for (int j = 0; j < 8; ++j) { a0[j] = 0.f; a1[j] = 0.f; a2[j] = 0.f; a3[j] = 0.f; }

    int e0 = 0, e1 = 0;
    if (active) {
        e0 = rs[node];
        e1 = rs[node + 1];
        f16x8 hv = *(const f16x8*)(Hs + (size_t)node * 64 + lg * 8);
#pragma unroll
        for (int j = 0; j < 8; ++j) a0[j] = (float)hv[j];
    }

    for (int base = e0; base < e1; base += 8) {
        int cnt = e1 - base;
        if (cnt > 8) cnt = 8;
        int sl = (base + lg < e1) ? csr[base + lg] : 0;
        int k = 0;
        for (; k + 4 <= cnt; k += 4) {
            int s0 = __shfl(sl, k + 0, 8);
            int s1 = __shfl(sl, k + 1, 8);
            int s2 = __shfl(sl, k + 2, 8);
            int s3 = __shfl(sl, k + 3, 8);
            f16x8 v0 = *(const f16x8*)(Hs + (size_t)s0 * 64 + lg * 8);
            f16x8 v1 = *(const f16x8*)(Hs + (size_t)s1 * 64 + lg * 8);
            f16x8 v2 = *(const f16x8*)(Hs + (size_t)s2 * 64 + lg * 8);
            f16x8 v3 = *(const f16x8*)(Hs + (size_t)s3 * 64 + lg * 8);
#pragma unroll
            for (int j = 0; j < 8; ++j) {
                a0[j] += (float)v0[j];
                a1[j] += (float)v1[j];
                a2[j] += (float)v2[j];
                a3[j] += (float)v3[j];
            }
        }
        for (; k < cnt; ++k) {
            int sk = __shfl(sl, k, 8);
            f16x8 v = *(const f16x8*)(Hs + (size_t)sk * 64 + lg * 8);
#pragma unroll
            for (int j = 0; j < 8; ++j) a0[j] += (float)v[j];
        }
    }

    if (active) {
        float d = dis[node];
        union { uint4 u; __half2 h[4]; } pk;
#pragma unroll
        for (int j = 0; j < 4; ++j) {
            float lo = d * ((a0[2 * j] + a1[2 * j]) + (a2[2 * j] + a3[2 * j]));
            float hi = d * ((a0[2 * j + 1] + a1[2 * j + 1]) + (a2[2 * j + 1] + a3[2 * j + 1]));
            pk.h[j] = __floats2half2_rn(lo, hi);
        }
        *(uint4*)(Z + ((size_t)s * n + node) * 64 + lg * 8) = pk.u;
    }
}

// ---------------- MFMA GEMM, W in LDS: H' = dis*relu(Z@W+b), in place -------
// 256 threads = 4 waves; block stages WTh+WTl (64KB) into XOR-swizzled LDS
// once, then processes GBR=256 rows (wave = 16 rows/iter, 4 iters).
// Z/H in slice-major [2][N][64]: A-frag slice = ks>>1, off = (ks&1)*32.
// mode 1 (last layer): emit t[row] = (relu-row . Wd) via 16-lane shfl reduce.
__global__ __launch_bounds__(256) void k_gemmw(const __half* __restrict__ Z,
                                               const __half* __restrict__ WTh,
                                               const __half* __restrict__ WTl,
                                               const float* __restrict__ b,
                                               const float* __restrict__ dis,
                                               __half* __restrict__ Hout,
                                               const float* __restrict__ Wd,
                                               float* __restrict__ tout,
                                               int mode, int n) {
    __shared__ __half ws[2][128][128];  // 64KB, swizzled
    int tid = threadIdx.x;
    int wave = tid >> 6, lane = tid & 63;
    int q = lane >> 4, r16 = lane & 15;

    // ---- stage W (coalesced 16B/thread x 16 passes) ----
#pragma unroll
    for (int p = 0; p < 16; ++p) {
        int idx = p * 256 + tid;       // 0..4095 16B-slots
        int slot = idx & 15;
        int col = (idx >> 4) & 127;
        int hl = idx >> 11;
        const __half* src = hl ? WTl : WTh;
        f16x8 v = *(const f16x8*)(src + (size_t)col * HW + slot * 8);
        *(f16x8*)(&ws[hl][col][(slot ^ (col & 7)) * 8]) = v;
    }
    __syncthreads();

    for (int rt = 0; rt < GBR / 64; ++rt) {
        int row0 = blockIdx.x * GBR + rt * 64 + wave * 16;
        if (row0 >= n) break;  // per-wave exit; no syncs below

        f16x8 afr[4];
#pragma unroll
        for (int ks = 0; ks < 4; ++ks) {
            int row = row0 + r16;
            row = row < n ? row : (n - 1);  // clamp; results discarded at store
            afr[ks] = *(const f16x8*)(Z + ((size_t)(ks >> 1) * n + row) * 64 +
                                      (ks & 1) * 32 + q * 8);
        }

        f32x4 acc[8];
#pragma unroll
        for (int nt = 0; nt < 8; ++nt) acc[nt] = (f32x4)0.f;
#pragma unroll
        for (int ks = 0; ks < 4; ++ks) {
            int sslot = ((ks * 4 + q) ^ (r16 & 7)) * 8;
#pragma unroll
            for (int nt = 0; nt < 8; ++nt) {
                int col = nt * 16 + r16;
                f16x8 bh = *(const f16x8*)(&ws[0][col][sslot]);
                f16x8 bl = *(const f16x8*)(&ws[1][col][sslot]);
                acc[nt] = __builtin_amdgcn_mfma_f32_16x16x32_f16(afr[ks], bh, acc[nt], 0, 0, 0);
                acc[nt] = __builtin_amdgcn_mfma_f32_16x16x32_f16(afr[ks], bl, acc[nt], 0, 0, 0);
            }
        }

        if (mode == 0) {
#pragma unroll
            for (int nt = 0; nt < 8; ++nt) {
                int col = nt * 16 + r16;
                int cs = col >> 6, c64 = col & 63;
                float bias = b[col];
#pragma unroll
                for (int r = 0; r < 4; ++r) {
                    int row = row0 + q * 4 + r;
                    if (row < n) {
                        float v = fmaxf(acc[nt][r] + bias, 0.f) * dis[row];
                        Hout[((size_t)cs * n + row) * 64 + c64] = __float2half_rn(v);
                    }
                }
            }
        } else {
            float pr[4] = {0.f, 0.f, 0.f, 0.f};
#pragma unroll
            for (int nt = 0; nt < 8; ++nt) {
                int col = nt * 16 + r16;
                float bias = b[col];
                float wd = Wd[col];
#pragma unroll
                for (int r = 0; r < 4; ++r)
                    pr[r] += fmaxf(acc[nt][r] + bias, 0.f) * wd;
            }
#pragma unroll
            for (int r = 0; r < 4; ++r) {
#pragma unroll
                for (int off = 1; off < 16; off <<= 1) pr[r] += __shfl_xor(pr[r], off, 16);
                if (r16 == 0) {
                    int row = row0 + q * 4 + r;
                    if (row < n) tout[row] = pr[r] * dis[row];
                }
            }
        }
    }
}

// ---------------- decoder output ----------------
__global__ void k_dec_out(const float* __restrict__ t, const int* __restrict__ rs,
                          const int* __restrict__ csr, const float* __restrict__ dis,
                          const float* __restrict__ bdec, const float* __restrict__ mask,
                          float* __restrict__ out, int n) {
    int i = blockIdx.x * 256 + threadIdx.x;
    if (i >= n) return;
    float acc = t[i];
    int e1 = rs[i + 1];
    for (int j = rs[i]; j < e1; ++j) acc += t[csr[j]];
    out[i] = (dis[i] * acc + bdec[0]) * mask[i];
}

// ---------------------------------------------------------------------------
static inline size_t align256(size_t x) { return (x + 255) & ~(size_t)255; }

extern "C" void kernel_launch(void* const* d_in, const int* in_sizes, int n_in,
                              void* d_out, int out_size, void* d_ws, size_t ws_size,
                              hipStream_t stream) {
    const float* x     = (const float*)d_in[0];
    const float* mask  = (const float*)d_in[1];
    const int*   ei    = (const int*)d_in[2];
    const float* W_enc = (const float*)d_in[3];
    const float* b_enc = (const float*)d_in[4];
    const float* W_p   = (const float*)d_in[5];
    const float* b_p   = (const float*)d_in[6];
    const float* W_dec = (const float*)d_in[7];
    const float* b_dec = (const float*)d_in[8];

    const int N = in_sizes[1];
    const int E = in_sizes[2] / 2;
    const int* srcA = ei;
    const int* dstA = ei + E;
    const int NB = (N + 127) >> 7;  // dst buckets of 128 nodes (<= NBMAX)

    char* p = (char*)d_ws;
    size_t off = 0;
    auto carve = [&](size_t bytes) {
        void* r = p + off;
        off += align256(bytes);
        return r;
    };
    int*      bcnt      = (int*)carve((size_t)NB * 4);
    int*      bstart    = (int*)carve((size_t)(NB + 1) * 4);
    int*      pcnt      = (int*)carve((size_t)PBLK * NB * 4);
    int*      soff      = (int*)carve((size_t)PBLK * NB * 4);
    int*      row_start = (int*)carve((size_t)(N + 1) * 4);
    unsigned* stage     = (unsigned*)carve((size_t)E * 4);
    int*      csr       = (int*)carve((size_t)E * 4);
    float*    dis       = (float*)carve((size_t)N * 4);
    float4*   x4        = (float4*)carve((size_t)N * 16);
    float4*   zx        = (float4*)carve((size_t)N * 16);
    float*    tdec      = (float*)carve((size_t)N * 4);
    __half*   WTh       = (__half*)carve((size_t)4 * HW * HW * 2);
    __half*   WTl       = (__half*)carve((size_t)4 * HW * HW * 2);
    __half*   HA        = (__half*)carve((size_t)N * HW * 2);
    __half*   HB        = (__half*)carve((size_t)N * HW * 2);

    const int gN   = (N + 255) / 256;
    const int nChunk = (N + 31) / 32;
    const int gAgg = ((nChunk + 3) / 4) * 8;
    const int gG   = (N + GBR - 1) / GBR;
    const int WPT  = 4 * HW * HW;

    // ---- CSR build (LDS-radix, no re-hist) + preps ----
    k_zero_i32<<<(NB + 255) / 256, 256, 0, stream>>>(bcnt, NB);
    k_histb<<<PBLK, 256, 0, stream>>>(dstA, bcnt, pcnt, NB, E, PBLK);
    k_bscan<<<1, 1024, 0, stream>>>(bcnt, bstart, NB, E);
    k_soff2<<<NB, PBLK, 0, stream>>>(pcnt, bstart, soff, NB);
    k_part<<<PBLK, 256, 0, stream>>>(srcA, dstA, soff, stage, NB, E, PBLK);
    k_build<<<NB, 256, 0, stream>>>(stage, bstart, x, row_start, dis, x4, csr, N, NB);
    k_prep_wt<<<(WPT + 255) / 256, 256, 0, stream>>>(W_p, WTh, WTl, WPT);

    // ---- encoder ----
    k_enc_agg<<<gN, 256, 0, stream>>>(x4, row_start, csr, dis, zx, N);
    k_enc_gemm<<<(N * HW + 255) / 256, 256, 0, stream>>>(zx, W_enc, b_enc, dis, HA, N);

    // ---- 4 processor layers: sliced agg(Hin->Hoth), gemmw in place on Hoth -
    __half* Hin = HA;
    __half* Hoth = HB;
    for (int l = 0; l < 4; ++l) {
        k_agg_s2<<<gAgg, 256, 0, stream>>>(Hin, row_start, csr, dis, Hoth, N);
        int mode = (l == 3) ? 1 : 0;
        k_gemmw<<<gG, 256, 0, stream>>>(Hoth, WTh + (size_t)l * HW * HW,
                                        WTl + (size_t)l * HW * HW,
                                        b_p + (size_t)l * HW, dis, Hoth,
                                        W_dec, tdec, mode, N);
        __half* t = Hin; Hin = Hoth; Hoth = t;
    }

    // ---- decoder output ----
    k_dec_out<<<gN, 256, 0, stream>>>(tdec, row_start, csr, dis, b_dec, mask,
                                      (float*)d_out, N);
}